// Round 1
// baseline (61.946 us; speedup 1.0000x reference)
//
#include <hip/hip_runtime.h>
#include <hip/hip_bf16.h>

// Fused recurrent net: ff = x@Win2E^T once; T steps of
//   actE = relu(ff + actI@WI2E^T); actI = relu(actE@WE2I^T);
// out = relu(actE_last@WE2Out^T).  All matmuls as C^T = W * act^T so the
// MFMA C/D col (lane&15) is the batch row in every stage.

typedef __bf16 bf16x8_t __attribute__((ext_vector_type(8)));
typedef __bf16 bf16x4_t __attribute__((ext_vector_type(4)));
typedef float f32x4_t __attribute__((ext_vector_type(4)));

#define THREADS 512

// LDS strides in BYTES (row padded by +8 bf16 elements = +16B -> conflict-free
// b64 writes / b128 reads, and keeps every row 16B-aligned).
#define S_WIN2E 272   // (128+8)*2
#define S_WE2OUT 272
#define S_WI2E 144    // (64+8)*2
#define S_WE2I 272
#define S_ACTE 272
#define S_ACTI 144

#define OFF_WIN2E 0
#define OFF_WE2OUT (OFF_WIN2E + 128 * S_WIN2E)        // 34816
#define OFF_WI2E (OFF_WE2OUT + 128 * S_WE2OUT)        // 69632
#define OFF_WE2I (OFF_WI2E + 128 * S_WI2E)            // 88064
#define OFF_ACTE (OFF_WE2I + 64 * S_WE2I)             // 105472 (8 waves x 16 x 272)
#define OFF_ACTI (OFF_ACTE + 8 * 16 * S_ACTE)         // 140288 (8 waves x 16 x 144)
#define SMEM_TOTAL (OFF_ACTI + 8 * 16 * S_ACTI)       // 158720 B

__device__ __forceinline__ f32x4_t mfma16(bf16x8_t a, bf16x8_t b, f32x4_t c) {
  return __builtin_amdgcn_mfma_f32_16x16x32_bf16(a, b, c, 0, 0, 0);
}

template <int ROWS, int COLS, int STRIDE_B>
__device__ __forceinline__ void stage_weight(const float* __restrict__ W,
                                             char* dst, int tid) {
  constexpr int TOTAL4 = ROWS * COLS / 4;       // multiples of THREADS here
#pragma unroll
  for (int it = 0; it < TOTAL4 / THREADS; ++it) {
    int e = (it * THREADS + tid) * 4;
    int r = e / COLS;
    int c = e % COLS;
    float4 v = *reinterpret_cast<const float4*>(W + e);
    bf16x4_t h;
    h[0] = (__bf16)v.x; h[1] = (__bf16)v.y;
    h[2] = (__bf16)v.z; h[3] = (__bf16)v.w;
    *reinterpret_cast<bf16x4_t*>(dst + r * STRIDE_B + c * 2) = h;
  }
}

__global__ __launch_bounds__(THREADS, 2) void unet_fused(
    const float* __restrict__ x,
    const float* __restrict__ Win2E,
    const float* __restrict__ WI2E,
    const float* __restrict__ WE2I,
    const float* __restrict__ WE2Out,
    const int* __restrict__ Tptr,
    float* __restrict__ out) {
  extern __shared__ char smem[];
  const int tid = threadIdx.x;

  // Stage all weights (fp32 global -> bf16 padded LDS), once per block.
  stage_weight<128, 128, S_WIN2E>(Win2E, smem + OFF_WIN2E, tid);
  stage_weight<128, 128, S_WE2OUT>(WE2Out, smem + OFF_WE2OUT, tid);
  stage_weight<128, 64, S_WI2E>(WI2E, smem + OFF_WI2E, tid);
  stage_weight<64, 128, S_WE2I>(WE2I, smem + OFF_WE2I, tid);
  __syncthreads();

  const int wid = tid >> 6;
  const int lane = tid & 63;
  const int m = lane & 15;    // batch row within the wave's 16-row tile
  const int kc = lane >> 4;   // k-chunk selector (8 contiguous k per chunk)
  const int T = *Tptr;

  char* actE = smem + OFF_ACTE + wid * (16 * S_ACTE);  // [16][128+8] bf16
  char* actI = smem + OFF_ACTI + wid * (16 * S_ACTI);  // [16][64+8] bf16

  // Hot-loop weight A-fragments -> registers (reused T times).
  bf16x8_t wi2e[8][2];  // M=N_E(128)->8 mtiles, K=N_I(64)->2 ksteps
#pragma unroll
  for (int mt = 0; mt < 8; ++mt)
#pragma unroll
    for (int ks = 0; ks < 2; ++ks)
      wi2e[mt][ks] = *reinterpret_cast<const bf16x8_t*>(
          smem + OFF_WI2E + (mt * 16 + m) * S_WI2E + (ks * 32 + kc * 8) * 2);

  bf16x8_t we2i[4][4];  // M=N_I(64)->4 mtiles, K=N_E(128)->4 ksteps
#pragma unroll
  for (int mt = 0; mt < 4; ++mt)
#pragma unroll
    for (int ks = 0; ks < 4; ++ks)
      we2i[mt][ks] = *reinterpret_cast<const bf16x8_t*>(
          smem + OFF_WE2I + (mt * 16 + m) * S_WE2I + (ks * 32 + kc * 8) * 2);

  const long row0 = ((long)blockIdx.x * 8 + wid) * 16;

  // x B-fragments: lane reads x[row0+m][ks*32+kc*8 .. +7] (fp32 -> bf16).
  bf16x8_t xb[4];
#pragma unroll
  for (int ks = 0; ks < 4; ++ks) {
    const float* xp = x + (row0 + m) * 128 + ks * 32 + kc * 8;
    float4 v0 = *reinterpret_cast<const float4*>(xp);
    float4 v1 = *reinterpret_cast<const float4*>(xp + 4);
    bf16x8_t h;
    h[0] = (__bf16)v0.x; h[1] = (__bf16)v0.y; h[2] = (__bf16)v0.z; h[3] = (__bf16)v0.w;
    h[4] = (__bf16)v1.x; h[5] = (__bf16)v1.y; h[6] = (__bf16)v1.z; h[7] = (__bf16)v1.w;
    xb[ks] = h;
  }

  // ff^T = Win2E * x^T  (kept in f32 regs for the whole kernel)
  f32x4_t ff[8];
#pragma unroll
  for (int mt = 0; mt < 8; ++mt) ff[mt] = (f32x4_t){0.f, 0.f, 0.f, 0.f};
#pragma unroll
  for (int ks = 0; ks < 4; ++ks) {
#pragma unroll
    for (int mt = 0; mt < 8; ++mt) {
      bf16x8_t a = *reinterpret_cast<const bf16x8_t*>(
          smem + OFF_WIN2E + (mt * 16 + m) * S_WIN2E + (ks * 32 + kc * 8) * 2);
      ff[mt] = mfma16(a, xb[ks], ff[mt]);
    }
  }

  f32x4_t acc_e[8];
#pragma unroll
  for (int mt = 0; mt < 8; ++mt) acc_e[mt] = ff[mt];  // step 0: actI = 0

  bf16x8_t eb[4];

  for (int t = 0;; ++t) {
    // relu(acc_e) -> bf16 -> LDS actE.  C/D layout: col=m, row=kc*4+j.
#pragma unroll
    for (int mt = 0; mt < 8; ++mt) {
      bf16x4_t h;
#pragma unroll
      for (int j = 0; j < 4; ++j) h[j] = (__bf16)fmaxf(acc_e[mt][j], 0.f);
      *reinterpret_cast<bf16x4_t*>(actE + m * S_ACTE + (mt * 16 + kc * 4) * 2) = h;
    }
    // actE B-fragments (also feed the output matmul after the loop).
#pragma unroll
    for (int ks = 0; ks < 4; ++ks)
      eb[ks] = *reinterpret_cast<const bf16x8_t*>(
          actE + m * S_ACTE + (ks * 32 + kc * 8) * 2);
    if (t == T - 1) break;  // last step's actI is dead

    // actI^T = relu(WE2I * actE^T)
    f32x4_t acc_i[4];
#pragma unroll
    for (int mt = 0; mt < 4; ++mt) acc_i[mt] = (f32x4_t){0.f, 0.f, 0.f, 0.f};
#pragma unroll
    for (int ks = 0; ks < 4; ++ks)
#pragma unroll
      for (int mt = 0; mt < 4; ++mt)
        acc_i[mt] = mfma16(we2i[mt][ks], eb[ks], acc_i[mt]);

#pragma unroll
    for (int mt = 0; mt < 4; ++mt) {
      bf16x4_t h;
#pragma unroll
      for (int j = 0; j < 4; ++j) h[j] = (__bf16)fmaxf(acc_i[mt][j], 0.f);
      *reinterpret_cast<bf16x4_t*>(actI + m * S_ACTI + (mt * 16 + kc * 4) * 2) = h;
    }
    bf16x8_t ib[2];
#pragma unroll
    for (int ks = 0; ks < 2; ++ks)
      ib[ks] = *reinterpret_cast<const bf16x8_t*>(
          actI + m * S_ACTI + (ks * 32 + kc * 8) * 2);

    // next actE(pre-relu) = ff + WI2E * actI^T
#pragma unroll
    for (int mt = 0; mt < 8; ++mt) acc_e[mt] = ff[mt];
#pragma unroll
    for (int ks = 0; ks < 2; ++ks)
#pragma unroll
      for (int mt = 0; mt < 8; ++mt)
        acc_e[mt] = mfma16(wi2e[mt][ks], ib[ks], acc_e[mt]);
  }

  // out^T = relu(WE2Out * actE_last^T); store fp32, coalesced float4.
#pragma unroll
  for (int mt = 0; mt < 8; ++mt) {
    f32x4_t o = (f32x4_t){0.f, 0.f, 0.f, 0.f};
#pragma unroll
    for (int ks = 0; ks < 4; ++ks) {
      bf16x8_t a = *reinterpret_cast<const bf16x8_t*>(
          smem + OFF_WE2OUT + (mt * 16 + m) * S_WE2OUT + (ks * 32 + kc * 8) * 2);
      o = mfma16(a, eb[ks], o);
    }
    f32x4_t r;
#pragma unroll
    for (int j = 0; j < 4; ++j) r[j] = fmaxf(o[j], 0.f);
    *reinterpret_cast<f32x4_t*>(out + (row0 + m) * 128 + mt * 16 + kc * 4) = r;
  }
}

extern "C" void kernel_launch(void* const* d_in, const int* in_sizes, int n_in,
                              void* d_out, int out_size, void* d_ws,
                              size_t ws_size, hipStream_t stream) {
  const float* x = (const float*)d_in[0];
  const float* Win2E = (const float*)d_in[1];
  const float* WI2E = (const float*)d_in[2];
  const float* WE2I = (const float*)d_in[3];
  const float* WE2Out = (const float*)d_in[4];
  const int* Tptr = (const int*)d_in[5];
  float* out = (float*)d_out;
  (void)n_in; (void)out_size; (void)d_ws; (void)ws_size;

  const int B = in_sizes[0] / 128;  // 131072
  // >64KB dynamic LDS needs the attribute bump (host-side, capture-safe).
  (void)hipFuncSetAttribute(reinterpret_cast<const void*>(unet_fused),
                            hipFuncAttributeMaxDynamicSharedMemorySize,
                            SMEM_TOTAL);
  dim3 grid(B / 128), block(THREADS);
  unet_fused<<<grid, block, SMEM_TOTAL, stream>>>(x, Win2E, WI2E, WE2I, WE2Out,
                                                  Tptr, out);
}